// Round 11
// baseline (100.458 us; speedup 1.0000x reference)
//
#include <hip/hip_runtime.h>
#include <hip/hip_bf16.h>

// CustomBernsteinLayer: out[b,o] = sum_{i,k} ber[b,i,k] * (coeffs[o,i,k]*weights[o,i])
// ber = (1+t)^k (1-t)^(8-k), t = tanh(x).  With e = exp2(2x*log2e):
//   (1-t) = 2/(e+1) = q, ratio r = e, p0 = q^8, ber_{k+1} = ber_k * r.
// bf16 MFMA GEMM M=16384 N=256 K=2304, per-lane in-register A-gen (validated).
// R18 == R17 resubmitted verbatim (R17's bench was an infra failure:
// "MI355X container failed twice"; no kernel result was produced).
// R17: phase-clustered inner loop (T3-lite + T5) on the R16 base (95.0us,
// gemm ~31us = 623 TF effective). All throughput floors (MFMA 9.3, LDS 11.5,
// VALU ~6us) are far below 31us and every schedule/occupancy probe was
// neutral -> residual is fine-grained ds_read->pack->MFMA interleave bubbles.
// Fix per m201/m218b mechanism: per k4-step, cluster all 8 ds_read_b128 into
// a read phase, s_barrier, then a pure pack+MFMA+recurrence phase inside
// s_setprio(1)/(0), s_barrier. LDS and MFMA pipes run in saturated bursts;
// setprio gets role-diversity (m190: null without phases; m218b: +21-39%
// with). Counted-vmcnt group headers (T4) unchanged; stage/x loads stay in
// flight across the new barriers. Kept: XCD-cohort swizzle (rg=blk&63),
// full-chunk x-prefetch with post-SETUP re-arm (R16-validated liveness).

#define BDIM 16384
#define IDIM 256
#define ODIM 256
#define NK 9
#define NSTEP 36
#define STEP_ELEMS (ODIM * 64)   // 16384 bf16 (32 KB) per K-step block

typedef short short8 __attribute__((ext_vector_type(8)));
typedef float floatx4 __attribute__((ext_vector_type(4)));

// ---------------------------------------------------------------------------
// prep (validated): wc[step][e] = bf16(coeffs[o,i,k]*weights[o,i]),
// e = (((o>>4)*2 + s)*64 + (o&15) + quad*16)*8 + j, i_local = s*32+quad*8+j,
// step = (i>>6)*9 + k. One coalesced 16B store per thread.
// ---------------------------------------------------------------------------
__global__ __launch_bounds__(256) void prep_wc2(const float* __restrict__ weights,
                                                const float* __restrict__ coeffs,
                                                ushort* __restrict__ wc) {
    int idx  = blockIdx.x * 256 + threadIdx.x;  // 73728 chunks
    int step = idx >> 11;
    int c    = idx & 2047;
    int big    = c >> 6;
    int lane_w = c & 63;
    int o    = (big >> 1) * 16 + (lane_w & 15);
    int s    = big & 1;
    int quad = lane_w >> 4;
    int ic = step / 9;
    int k  = step - ic * 9;
    int i0 = ic * 64 + s * 32 + quad * 8;

    const float* cp = coeffs + (size_t)(o * IDIM + i0) * NK + k;
    float4 w0 = *(const float4*)(weights + o * IDIM + i0);
    float4 w1 = *(const float4*)(weights + o * IDIM + i0 + 4);
    float wv[8] = {w0.x, w0.y, w0.z, w0.w, w1.x, w1.y, w1.z, w1.w};

    union { ushort us[8]; int4 v; __hip_bfloat162 h2[4]; } pk;
#pragma unroll
    for (int j = 0; j < 8; j += 2) {
        float a = cp[(size_t)j * NK] * wv[j];
        float b = cp[(size_t)(j + 1) * NK] * wv[j + 1];
        pk.h2[j >> 1] = __float22bfloat162_rn(make_float2(a, b));
    }
    *(int4*)(wc + (size_t)step * STEP_ELEMS + (size_t)c * 8) = pk.v;
}

// ---------------------------------------------------------------------------
// GEMM: 256 blocks x 512 threads (8 waves), 1 block/CU (96 KB LDS).
//   rg = blk & 63 -> rows rg*256 .. +255  (XCD = blk%8 = rg%8: all cg-
//   duplicates of a row-group share one XCD/L2)
//   cg = blk >> 6 -> cols cg*64 .. +63 (whole block)
//   wave w: rows rg*256 + w*32 .. +31 (m=2 tiles of 16)
// Per-lane A state: rows rb + m*16 + (lane&15), m in {0,1};
//   i_local = s*32 + (lane>>4)*8 + j.
// B: cg-slice of each step is a contiguous 8 KB of wc; groups of 4 steps
// (32 KB) staged into Blds[3] TWO groups ahead via global_load_lds; fragment
// (n,s) of step g*4+k4 at Blds[g%3][k4*4096 + (n*2+s)*512 + lane*8] (b128).
// Raw s_barrier + counted vmcnt per group header; never drains mid-loop.
// Inner loop: per k4, {8 ds_read} | barrier | {setprio(1) pack+MFMA+rec
// setprio(0)} | barrier  (phase-clustered).
// ---------------------------------------------------------------------------
__global__ __launch_bounds__(512, 2) void bern_gemm(const float* __restrict__ x,
                                                    const ushort* __restrict__ wc,
                                                    float* __restrict__ out) {
    __shared__ ushort Blds[3][16384];   // 3 x 32 KB

    const int tid  = threadIdx.x;
    const int wave = tid >> 6;          // 0..7
    const int lane = tid & 63;
    const int cg   = blockIdx.x >> 6;   // 0..3 (swizzled: co-XCD duplicates)
    const int rb   = (blockIdx.x & 63) * 256 + wave * 32;
    const int lrow = lane & 15;
    const int jseg = (lane >> 4) * 8;      // 0,8,16,24

    float p[2][2][8];    // [m][s][j]: running ber
    float r[2][2][8];    // ratio e = exp2(2x log2 e), live all chunk
    float xq[2][2][8];   // raw-x prefetch buffer (filled a full chunk early)
    floatx4 acc[2][4];
    floatx4 zero = {0.0f, 0.0f, 0.0f, 0.0f};
#pragma unroll
    for (int m = 0; m < 2; ++m)
#pragma unroll
        for (int n = 0; n < 4; ++n)
            acc[m][n] = zero;

    // load raw x for chunk ic_ into xq (xq is dead when this runs)
#define LOAD_XQ(ic_)                                                            \
    {                                                                           \
        _Pragma("unroll") for (int m = 0; m < 2; ++m)                           \
        _Pragma("unroll") for (int s = 0; s < 2; ++s) {                         \
            const float* xp = x + (size_t)(rb + m * 16 + lrow) * IDIM           \
                              + (ic_) * 64 + s * 32 + jseg;                     \
            float4 v0 = *(const float4*)(xp);                                   \
            float4 v1 = *(const float4*)(xp + 4);                               \
            xq[m][s][0] = v0.x; xq[m][s][1] = v0.y;                             \
            xq[m][s][2] = v0.z; xq[m][s][3] = v0.w;                             \
            xq[m][s][4] = v1.x; xq[m][s][5] = v1.y;                             \
            xq[m][s][6] = v1.z; xq[m][s][7] = v1.w;                             \
        }                                                                       \
    }

    // xq holds raw x -> p = q^8, r = ratio (p,r dead when this runs)
#define SETUP_FROM_XQ()                                                         \
    {                                                                           \
        _Pragma("unroll") for (int m = 0; m < 2; ++m)                           \
        _Pragma("unroll") for (int s = 0; s < 2; ++s)                           \
        _Pragma("unroll") for (int e = 0; e < 8; ++e) {                         \
            float t  = __builtin_amdgcn_exp2f(xq[m][s][e] * 2.8853900817779268f);\
            float q  = 2.0f * __builtin_amdgcn_rcpf(t + 1.0f);                  \
            float q2 = q * q;                                                   \
            float q4 = q2 * q2;                                                 \
            p[m][s][e] = q4 * q4;                                               \
            r[m][s][e] = t;                                                     \
        }                                                                       \
    }

    // stage group g_ (4 steps, 32 KB cg-slice) into Blds[b_]; 512 threads x
    // 16B cover one step's 8 KB slice per q-round (4 loads/thread total).
#define STAGE(g_, b_)                                                           \
    {                                                                           \
        _Pragma("unroll") for (int q = 0; q < 4; ++q) {                         \
            int st  = (g_) * 4 + q;                                             \
            int off = wave * 512 + lane * 8;                                    \
            const ushort* sp = wc + (size_t)st * STEP_ELEMS + cg * 4096 + off;  \
            ushort* dp = &Blds[b_][q * 4096 + off];                             \
            __builtin_amdgcn_global_load_lds(                                   \
                (const __attribute__((address_space(1))) void*)sp,              \
                (__attribute__((address_space(3))) void*)dp, 16, 0, 0);         \
        }                                                                       \
    }

#define WAITV(n_) asm volatile("s_waitcnt vmcnt(" #n_ ")" ::: "memory")

    LOAD_XQ(0);
    SETUP_FROM_XQ();   // compiler waits xq0 here; then loads below
    STAGE(0, 0);       // 4 loads in flight
    STAGE(1, 1);       // 8 loads in flight

#pragma unroll
    for (int g = 0; g < 9; ++g) {
        // wait for stage(g) (oldest). Loads issued after stage(g)'s last:
        // g0: stage1=4            | g1: xq1(8)+stage2=12 | g2: stage3=4
        // g3: stage4+xq2=12       | g4: xq2(8)+stage5=12 | g5: stage6+xq3=12
        // g6: xq3(8)+stage7=12    | g7: stage8=4         | g8: 0
        if (g == 0 || g == 2 || g == 7) { WAITV(4); }
        else if (g == 8)                { WAITV(0); }
        else                            { WAITV(12); }
        __builtin_amdgcn_s_barrier();
        __builtin_amdgcn_sched_barrier(0);

        // chunk-1 x prefetch at g=0 header (xq dead since prologue SETUP);
        // chunks 2,3 are prefetched inside the k4 loop right after their
        // predecessor's SETUP consumes xq (steps 8, 17).
        if (g == 0) LOAD_XQ(1);
        if (g < 7) STAGE(g + 2, (g + 2) % 3);

        const int bg = g % 3;
#pragma unroll
        for (int k4 = 0; k4 < 4; ++k4) {
            const int step = g * 4 + k4;
            const int kin = step % 9;

            // ---- phase A: all 8 B-fragment reads for this step ----
            short8 bfr[2][4];
#pragma unroll
            for (int s = 0; s < 2; ++s)
#pragma unroll
                for (int n = 0; n < 4; ++n)
                    bfr[s][n] = *(const short8*)&Blds[bg]
                        [k4 * 4096 + (n * 2 + s) * 512 + lane * 8];

            __builtin_amdgcn_s_barrier();

            // ---- phase B: pure pack + MFMA + recurrence, high prio ----
            __builtin_amdgcn_s_setprio(1);
#pragma unroll
            for (int s = 0; s < 2; ++s) {
#pragma unroll
                for (int m = 0; m < 2; ++m) {
                    union { ushort us[8]; short8 v; __hip_bfloat162 h2[4]; } pk;
#pragma unroll
                    for (int e = 0; e < 8; e += 2) {
                        pk.h2[e >> 1] = __float22bfloat162_rn(
                            make_float2(p[m][s][e], p[m][s][e + 1]));
                    }
#pragma unroll
                    for (int n = 0; n < 4; ++n)
                        acc[m][n] = __builtin_amdgcn_mfma_f32_16x16x32_bf16(
                            pk.v, bfr[s][n], acc[m][n], 0, 0, 0);
                    if (kin < NK - 1)
#pragma unroll
                        for (int e = 0; e < 8; ++e) p[m][s][e] *= r[m][s][e];
                }
            }
            __builtin_amdgcn_s_setprio(0);

            // chunk boundary (kin==8): old p,r dead; build next chunk's
            // basis from prefetched xq, THEN immediately re-arm xq with the
            // following chunk's x (R16-validated liveness).
            if (step == 8 || step == 17 || step == 26) {
                SETUP_FROM_XQ();
                if (step == 8)  LOAD_XQ(2);
                if (step == 17) LOAD_XQ(3);
            }

            __builtin_amdgcn_s_barrier();
        }
    }

    // ---- epilogue: C/D layout col=lane&15, row=(lane>>4)*4+reg ----
#pragma unroll
    for (int m = 0; m < 2; ++m) {
#pragma unroll
        for (int n = 0; n < 4; ++n) {
            int col   = cg * 64 + n * 16 + (lane & 15);
            int rbase = rb + m * 16 + (lane >> 4) * 4;
#pragma unroll
            for (int reg = 0; reg < 4; ++reg) {
                out[(size_t)(rbase + reg) * ODIM + col] = acc[m][n][reg];
            }
        }
    }
#undef LOAD_XQ
#undef SETUP_FROM_XQ
#undef STAGE
#undef WAITV
}

extern "C" void kernel_launch(void* const* d_in, const int* in_sizes, int n_in,
                              void* d_out, int out_size, void* d_ws, size_t ws_size,
                              hipStream_t stream) {
    const float* x       = (const float*)d_in[0];   // [B, I]
    const float* weights = (const float*)d_in[1];   // [O, I]
    const float* coeffs  = (const float*)d_in[2];   // [O, I, 9]
    float* out = (float*)d_out;                     // [B, O]
    ushort* wc = (ushort*)d_ws;                     // 36 * 32 KB = 1.13 MB

    prep_wc2<<<288, 256, 0, stream>>>(weights, coeffs, wc);
    bern_gemm<<<256, 512, 0, stream>>>(x, wc, out);
}

// Round 12
// 94.391 us; speedup vs baseline: 1.0643x; 1.0643x over previous
//
#include <hip/hip_runtime.h>
#include <hip/hip_bf16.h>

// CustomBernsteinLayer: out[b,o] = sum_{i,k} ber[b,i,k] * (coeffs[o,i,k]*weights[o,i])
// ber = (1+t)^k (1-t)^(8-k), t = tanh(x).  With e = exp2(2x*log2e):
//   (1-t) = 2/(e+1) = q, ratio r = e, p0 = q^8, ber_{k+1} = ber_k * r.
// bf16 MFMA GEMM M=16384 N=256 K=2304, per-lane in-register A-gen (validated).
// R19: (1) revert gemm to R16 exactly (95.0us; R18's phase-clustering
// regressed to 100.5 -> falsified, m233 barrier-cost mode). (2) rewrite prep.
// Ledger arithmetic (R10/R13/R16 all give fixed-residual ~20.4us) pins
// prep_wc2 at ~13us: it does 8 scalar loads/thread scattered at 9216B lane
// stride (o varies per lane) at ~1 block/CU -- a latency-bound gather.
// prep_wc3: block = o, thread = i; each thread reads its 9 k-coeffs
// CONTIGUOUSLY (36B; lanes stride 36B -> 2304B/wave coalesced bursts) + 1
// weight, scatters 9 bf16 ushort stores (fire-and-forget, 16B runs/wave).
// Output layout identical to validated prep_wc2 (index-derived).

#define BDIM 16384
#define IDIM 256
#define ODIM 256
#define NK 9
#define NSTEP 36
#define STEP_ELEMS (ODIM * 64)   // 16384 bf16 (32 KB) per K-step block

typedef short short8 __attribute__((ext_vector_type(8)));
typedef float floatx4 __attribute__((ext_vector_type(4)));

// ---------------------------------------------------------------------------
// prep_wc3: wc[(ic*9+k)*16384 + c*8 + (i&7)] = bf16(coeffs[o,i,k]*weights[o,i])
// with c = ((o>>4)*2 + ((i>>5)&1))*64 + ((i>>3)&3)*16 + (o&15), ic = i>>6.
// (Same mapping as validated prep_wc2, re-derived per-element.)
// One block per o (256 blocks x 256 threads); thread = i.
// Reads: 9 contiguous floats/thread (lane stride 36 B) + 1 weight (coalesced).
// Writes: 9 x ushort scatter (8-lane 16B runs per wave-store instruction).
// ---------------------------------------------------------------------------
__global__ __launch_bounds__(256) void prep_wc3(const float* __restrict__ weights,
                                                const float* __restrict__ coeffs,
                                                ushort* __restrict__ wc) {
    const int o = blockIdx.x;          // 0..255
    const int i = threadIdx.x;         // 0..255
    const int idx = o * IDIM + i;

    const float* cp = coeffs + (size_t)idx * NK;   // 9 contiguous floats
    const float w = weights[idx];

    const int ic   = i >> 6;
    const int s    = (i >> 5) & 1;
    const int quad = (i >> 3) & 3;
    const int j    = i & 7;
    const int c    = ((o >> 4) * 2 + s) * 64 + quad * 16 + (o & 15);

    ushort* base = wc + (size_t)ic * NK * STEP_ELEMS + c * 8 + j;

#pragma unroll
    for (int k = 0; k < NK; ++k) {
        float v = cp[k] * w;
        union { float f; unsigned int u; } cv;
        cv.f = v;
        unsigned int b = cv.u;
        ushort h = (ushort)((b + 0x7FFFu + ((b >> 16) & 1u)) >> 16);  // RN
        base[(size_t)k * STEP_ELEMS] = h;
    }
}

// ---------------------------------------------------------------------------
// GEMM (== R16, validated 95.0us): 256 blocks x 512 threads (8 waves),
// 1 block/CU (96 KB LDS).
//   rg = blk & 63 -> rows rg*256 .. +255  (XCD = blk%8 = rg%8: all cg-
//   duplicates of a row-group share one XCD/L2)
//   cg = blk >> 6 -> cols cg*64 .. +63 (whole block)
//   wave w: rows rg*256 + w*32 .. +31 (m=2 tiles of 16)
// Per-lane A state: rows rb + m*16 + (lane&15), m in {0,1};
//   i_local = s*32 + (lane>>4)*8 + j.
// B: cg-slice of each step is a contiguous 8 KB of wc; groups of 4 steps
// (32 KB) staged into Blds[3] TWO groups ahead via global_load_lds; fragment
// (n,s) of step g*4+k4 at Blds[g%3][k4*4096 + (n*2+s)*512 + lane*8] (b128).
// Raw s_barrier + counted vmcnt per group header; never drains mid-loop.
// ---------------------------------------------------------------------------
__global__ __launch_bounds__(512, 2) void bern_gemm(const float* __restrict__ x,
                                                    const ushort* __restrict__ wc,
                                                    float* __restrict__ out) {
    __shared__ ushort Blds[3][16384];   // 3 x 32 KB

    const int tid  = threadIdx.x;
    const int wave = tid >> 6;          // 0..7
    const int lane = tid & 63;
    const int cg   = blockIdx.x >> 6;   // 0..3 (swizzled: co-XCD duplicates)
    const int rb   = (blockIdx.x & 63) * 256 + wave * 32;
    const int lrow = lane & 15;
    const int jseg = (lane >> 4) * 8;      // 0,8,16,24

    float p[2][2][8];    // [m][s][j]: running ber
    float r[2][2][8];    // ratio e = exp2(2x log2 e), live all chunk
    float xq[2][2][8];   // raw-x prefetch buffer (filled a full chunk early)
    floatx4 acc[2][4];
    floatx4 zero = {0.0f, 0.0f, 0.0f, 0.0f};
#pragma unroll
    for (int m = 0; m < 2; ++m)
#pragma unroll
        for (int n = 0; n < 4; ++n)
            acc[m][n] = zero;

    // load raw x for chunk ic_ into xq (xq is dead when this runs)
#define LOAD_XQ(ic_)                                                            \
    {                                                                           \
        _Pragma("unroll") for (int m = 0; m < 2; ++m)                           \
        _Pragma("unroll") for (int s = 0; s < 2; ++s) {                         \
            const float* xp = x + (size_t)(rb + m * 16 + lrow) * IDIM           \
                              + (ic_) * 64 + s * 32 + jseg;                     \
            float4 v0 = *(const float4*)(xp);                                   \
            float4 v1 = *(const float4*)(xp + 4);                               \
            xq[m][s][0] = v0.x; xq[m][s][1] = v0.y;                             \
            xq[m][s][2] = v0.z; xq[m][s][3] = v0.w;                             \
            xq[m][s][4] = v1.x; xq[m][s][5] = v1.y;                             \
            xq[m][s][6] = v1.z; xq[m][s][7] = v1.w;                             \
        }                                                                       \
    }

    // xq holds raw x -> p = q^8, r = ratio (p,r dead when this runs)
#define SETUP_FROM_XQ()                                                         \
    {                                                                           \
        _Pragma("unroll") for (int m = 0; m < 2; ++m)                           \
        _Pragma("unroll") for (int s = 0; s < 2; ++s)                           \
        _Pragma("unroll") for (int e = 0; e < 8; ++e) {                         \
            float t  = __builtin_amdgcn_exp2f(xq[m][s][e] * 2.8853900817779268f);\
            float q  = 2.0f * __builtin_amdgcn_rcpf(t + 1.0f);                  \
            float q2 = q * q;                                                   \
            float q4 = q2 * q2;                                                 \
            p[m][s][e] = q4 * q4;                                               \
            r[m][s][e] = t;                                                     \
        }                                                                       \
    }

    // stage group g_ (4 steps, 32 KB cg-slice) into Blds[b_]; 512 threads x
    // 16B cover one step's 8 KB slice per q-round (4 loads/thread total).
#define STAGE(g_, b_)                                                           \
    {                                                                           \
        _Pragma("unroll") for (int q = 0; q < 4; ++q) {                         \
            int st  = (g_) * 4 + q;                                             \
            int off = wave * 512 + lane * 8;                                    \
            const ushort* sp = wc + (size_t)st * STEP_ELEMS + cg * 4096 + off;  \
            ushort* dp = &Blds[b_][q * 4096 + off];                             \
            __builtin_amdgcn_global_load_lds(                                   \
                (const __attribute__((address_space(1))) void*)sp,              \
                (__attribute__((address_space(3))) void*)dp, 16, 0, 0);         \
        }                                                                       \
    }

#define WAITV(n_) asm volatile("s_waitcnt vmcnt(" #n_ ")" ::: "memory")

    LOAD_XQ(0);
    SETUP_FROM_XQ();   // compiler waits xq0 here; then loads below
    STAGE(0, 0);       // 4 loads in flight
    STAGE(1, 1);       // 8 loads in flight

#pragma unroll
    for (int g = 0; g < 9; ++g) {
        // wait for stage(g) (oldest). Loads issued after stage(g)'s last:
        // g0: stage1=4            | g1: xq1(8)+stage2=12 | g2: stage3=4
        // g3: stage4+xq2=12       | g4: xq2(8)+stage5=12 | g5: stage6+xq3=12
        // g6: xq3(8)+stage7=12    | g7: stage8=4         | g8: 0
        if (g == 0 || g == 2 || g == 7) { WAITV(4); }
        else if (g == 8)                { WAITV(0); }
        else                            { WAITV(12); }
        __builtin_amdgcn_s_barrier();
        __builtin_amdgcn_sched_barrier(0);

        // chunk-1 x prefetch at g=0 header (xq dead since prologue SETUP);
        // chunks 2,3 are prefetched inside the k4 loop right after their
        // predecessor's SETUP consumes xq (steps 8, 17).
        if (g == 0) LOAD_XQ(1);
        if (g < 7) STAGE(g + 2, (g + 2) % 3);

        const int bg = g % 3;
#pragma unroll
        for (int k4 = 0; k4 < 4; ++k4) {
            const int step = g * 4 + k4;
            const int kin = step % 9;

#pragma unroll
            for (int s = 0; s < 2; ++s) {
                // B fragments for this (step, s) from LDS, reused by 2 m's
                short8 bfr[4];
#pragma unroll
                for (int n = 0; n < 4; ++n)
                    bfr[n] = *(const short8*)&Blds[bg]
                        [k4 * 4096 + (n * 2 + s) * 512 + lane * 8];

#pragma unroll
                for (int m = 0; m < 2; ++m) {
                    union { ushort us[8]; short8 v; __hip_bfloat162 h2[4]; } pk;
#pragma unroll
                    for (int e = 0; e < 8; e += 2) {
                        pk.h2[e >> 1] = __float22bfloat162_rn(
                            make_float2(p[m][s][e], p[m][s][e + 1]));
                    }
#pragma unroll
                    for (int n = 0; n < 4; ++n)
                        acc[m][n] = __builtin_amdgcn_mfma_f32_16x16x32_bf16(
                            pk.v, bfr[n], acc[m][n], 0, 0, 0);
                    if (kin < NK - 1)
#pragma unroll
                        for (int e = 0; e < 8; ++e) p[m][s][e] *= r[m][s][e];
                }
            }

            // chunk boundary (kin==8): old p,r dead; build next chunk's
            // basis from prefetched xq, THEN immediately re-arm xq with the
            // following chunk's x (R16-validated liveness).
            if (step == 8 || step == 17 || step == 26) {
                SETUP_FROM_XQ();
                if (step == 8)  LOAD_XQ(2);
                if (step == 17) LOAD_XQ(3);
            }
        }
    }

    // ---- epilogue: C/D layout col=lane&15, row=(lane>>4)*4+reg ----
#pragma unroll
    for (int m = 0; m < 2; ++m) {
#pragma unroll
        for (int n = 0; n < 4; ++n) {
            int col   = cg * 64 + n * 16 + (lane & 15);
            int rbase = rb + m * 16 + (lane >> 4) * 4;
#pragma unroll
            for (int reg = 0; reg < 4; ++reg) {
                out[(size_t)(rbase + reg) * ODIM + col] = acc[m][n][reg];
            }
        }
    }
#undef LOAD_XQ
#undef SETUP_FROM_XQ
#undef STAGE
#undef WAITV
}

extern "C" void kernel_launch(void* const* d_in, const int* in_sizes, int n_in,
                              void* d_out, int out_size, void* d_ws, size_t ws_size,
                              hipStream_t stream) {
    const float* x       = (const float*)d_in[0];   // [B, I]
    const float* weights = (const float*)d_in[1];   // [O, I]
    const float* coeffs  = (const float*)d_in[2];   // [O, I, 9]
    float* out = (float*)d_out;                     // [B, O]
    ushort* wc = (ushort*)d_ws;                     // 36 * 32 KB = 1.13 MB

    prep_wc3<<<256, 256, 0, stream>>>(weights, coeffs, wc);
    bern_gemm<<<256, 512, 0, stream>>>(x, wc, out);
}

// Round 13
// 93.620 us; speedup vs baseline: 1.0730x; 1.0082x over previous
//
#include <hip/hip_runtime.h>
#include <hip/hip_bf16.h>

// CustomBernsteinLayer: out[b,o] = sum_{i,k} ber[b,i,k] * (coeffs[o,i,k]*weights[o,i])
// ber = (1+t)^k (1-t)^(8-k), t = tanh(x).  With e = exp2(2x*log2e):
//   (1-t) = 2/(e+1) = q, ratio r = e, p0 = q^8, ber_{k+1} = ber_k * r.
// bf16 MFMA GEMM M=16384 N=256 K=2304, per-lane in-register A-gen (validated).
// R20: half-step B-fragment register pipeline on the R19 base (94.4us).
// Lever scoreboard: schedules 0, occupancy 0, phase-barriers -5.5, x-latency
// fixes -3.5 -> only removing dependent-load latency ever helped. Remaining
// per-step dependency: 8 ds_read_b128 -> same step's MFMAs (both SIMD waves
// barrier-synced into the same phase -> ~120cyc LDS round-trip on the
// critical path 4x/group). Fix: read (k4,s+1)'s fragments BEFORE (k4,s)'s
// MFMAs (fully-unrolled static double-bank rotation, +8 VGPR ~116 <= 128
// cap); exposed lgkm wait drops to once per group (post-barrier).
// Kept verbatim: prep_wc3, XCD-cohort swizzle, counted-vmcnt headers,
// full-chunk xq prefetch with post-SETUP re-arm.

#define BDIM 16384
#define IDIM 256
#define ODIM 256
#define NK 9
#define NSTEP 36
#define STEP_ELEMS (ODIM * 64)   // 16384 bf16 (32 KB) per K-step block

typedef short short8 __attribute__((ext_vector_type(8)));
typedef float floatx4 __attribute__((ext_vector_type(4)));

// ---------------------------------------------------------------------------
// prep_wc3 (R19-validated): wc[(ic*9+k)*16384 + c*8 + (i&7)] =
//   bf16(coeffs[o,i,k]*weights[o,i]),
// c = ((o>>4)*2 + ((i>>5)&1))*64 + ((i>>3)&3)*16 + (o&15), ic = i>>6.
// Block = o, thread = i: 9 contiguous float reads/thread + 1 weight;
// 9 scattered ushort stores (16B runs per wave-store).
// ---------------------------------------------------------------------------
__global__ __launch_bounds__(256) void prep_wc3(const float* __restrict__ weights,
                                                const float* __restrict__ coeffs,
                                                ushort* __restrict__ wc) {
    const int o = blockIdx.x;          // 0..255
    const int i = threadIdx.x;         // 0..255
    const int idx = o * IDIM + i;

    const float* cp = coeffs + (size_t)idx * NK;   // 9 contiguous floats
    const float w = weights[idx];

    const int ic   = i >> 6;
    const int s    = (i >> 5) & 1;
    const int quad = (i >> 3) & 3;
    const int j    = i & 7;
    const int c    = ((o >> 4) * 2 + s) * 64 + quad * 16 + (o & 15);

    ushort* base = wc + (size_t)ic * NK * STEP_ELEMS + c * 8 + j;

#pragma unroll
    for (int k = 0; k < NK; ++k) {
        float v = cp[k] * w;
        union { float f; unsigned int u; } cv;
        cv.f = v;
        unsigned int b = cv.u;
        ushort h = (ushort)((b + 0x7FFFu + ((b >> 16) & 1u)) >> 16);  // RN
        base[(size_t)k * STEP_ELEMS] = h;
    }
}

// ---------------------------------------------------------------------------
// GEMM: 256 blocks x 512 threads (8 waves), 1 block/CU (96 KB LDS).
//   rg = blk & 63 -> rows rg*256 .. +255  (XCD = blk%8 = rg%8: all cg-
//   duplicates of a row-group share one XCD/L2)
//   cg = blk >> 6 -> cols cg*64 .. +63 (whole block)
//   wave w: rows rg*256 + w*32 .. +31 (m=2 tiles of 16)
// Per-lane A state: rows rb + m*16 + (lane&15), m in {0,1};
//   i_local = s*32 + (lane>>4)*8 + j.
// B: cg-slice of each step is a contiguous 8 KB of wc; groups of 4 steps
// (32 KB) staged into Blds[3] TWO groups ahead via global_load_lds; fragment
// (n,s) of step g*4+k4 at Blds[g%3][k4*4096 + (n*2+s)*512 + lane*8] (b128).
// Raw s_barrier + counted vmcnt per group header; never drains mid-loop.
// Inner: half-step register pipeline — fragments for (k4,s') are read one
// half-step early; MFMAs never wait on a fresh LDS round-trip mid-group.
// ---------------------------------------------------------------------------
__global__ __launch_bounds__(512, 2) void bern_gemm(const float* __restrict__ x,
                                                    const ushort* __restrict__ wc,
                                                    float* __restrict__ out) {
    __shared__ ushort Blds[3][16384];   // 3 x 32 KB

    const int tid  = threadIdx.x;
    const int wave = tid >> 6;          // 0..7
    const int lane = tid & 63;
    const int cg   = blockIdx.x >> 6;   // 0..3 (swizzled: co-XCD duplicates)
    const int rb   = (blockIdx.x & 63) * 256 + wave * 32;
    const int lrow = lane & 15;
    const int jseg = (lane >> 4) * 8;      // 0,8,16,24

    float p[2][2][8];    // [m][s][j]: running ber
    float r[2][2][8];    // ratio e = exp2(2x log2 e), live all chunk
    float xq[2][2][8];   // raw-x prefetch buffer (filled a full chunk early)
    floatx4 acc[2][4];
    floatx4 zero = {0.0f, 0.0f, 0.0f, 0.0f};
#pragma unroll
    for (int m = 0; m < 2; ++m)
#pragma unroll
        for (int n = 0; n < 4; ++n)
            acc[m][n] = zero;

    // load raw x for chunk ic_ into xq (xq is dead when this runs)
#define LOAD_XQ(ic_)                                                            \
    {                                                                           \
        _Pragma("unroll") for (int m = 0; m < 2; ++m)                           \
        _Pragma("unroll") for (int s = 0; s < 2; ++s) {                         \
            const float* xp = x + (size_t)(rb + m * 16 + lrow) * IDIM           \
                              + (ic_) * 64 + s * 32 + jseg;                     \
            float4 v0 = *(const float4*)(xp);                                   \
            float4 v1 = *(const float4*)(xp + 4);                               \
            xq[m][s][0] = v0.x; xq[m][s][1] = v0.y;                             \
            xq[m][s][2] = v0.z; xq[m][s][3] = v0.w;                             \
            xq[m][s][4] = v1.x; xq[m][s][5] = v1.y;                             \
            xq[m][s][6] = v1.z; xq[m][s][7] = v1.w;                             \
        }                                                                       \
    }

    // xq holds raw x -> p = q^8, r = ratio (p,r dead when this runs)
#define SETUP_FROM_XQ()                                                         \
    {                                                                           \
        _Pragma("unroll") for (int m = 0; m < 2; ++m)                           \
        _Pragma("unroll") for (int s = 0; s < 2; ++s)                           \
        _Pragma("unroll") for (int e = 0; e < 8; ++e) {                         \
            float t  = __builtin_amdgcn_exp2f(xq[m][s][e] * 2.8853900817779268f);\
            float q  = 2.0f * __builtin_amdgcn_rcpf(t + 1.0f);                  \
            float q2 = q * q;                                                   \
            float q4 = q2 * q2;                                                 \
            p[m][s][e] = q4 * q4;                                               \
            r[m][s][e] = t;                                                     \
        }                                                                       \
    }

    // stage group g_ (4 steps, 32 KB cg-slice) into Blds[b_]; 512 threads x
    // 16B cover one step's 8 KB slice per q-round (4 loads/thread total).
#define STAGE(g_, b_)                                                           \
    {                                                                           \
        _Pragma("unroll") for (int q = 0; q < 4; ++q) {                         \
            int st  = (g_) * 4 + q;                                             \
            int off = wave * 512 + lane * 8;                                    \
            const ushort* sp = wc + (size_t)st * STEP_ELEMS + cg * 4096 + off;  \
            ushort* dp = &Blds[b_][q * 4096 + off];                             \
            __builtin_amdgcn_global_load_lds(                                   \
                (const __attribute__((address_space(1))) void*)sp,              \
                (__attribute__((address_space(3))) void*)dp, 16, 0, 0);         \
        }                                                                       \
    }

#define WAITV(n_) asm volatile("s_waitcnt vmcnt(" #n_ ")" ::: "memory")

    // read the 4 n-fragments of (k4_, s_) from the current group buffer
#define READ_BFR(dst_, bg_, k4_, s_)                                            \
    {                                                                           \
        _Pragma("unroll") for (int n = 0; n < 4; ++n)                           \
            dst_[n] = *(const short8*)&Blds[bg_]                                \
                [(k4_) * 4096 + (n * 2 + (s_)) * 512 + lane * 8];               \
    }

    LOAD_XQ(0);
    SETUP_FROM_XQ();   // compiler waits xq0 here; then loads below
    STAGE(0, 0);       // 4 loads in flight
    STAGE(1, 1);       // 8 loads in flight

#pragma unroll
    for (int g = 0; g < 9; ++g) {
        // wait for stage(g) (oldest). Loads issued after stage(g)'s last:
        // g0: stage1=4            | g1: xq1(8)+stage2=12 | g2: stage3=4
        // g3: stage4+xq2=12       | g4: xq2(8)+stage5=12 | g5: stage6+xq3=12
        // g6: xq3(8)+stage7=12    | g7: stage8=4         | g8: 0
        if (g == 0 || g == 2 || g == 7) { WAITV(4); }
        else if (g == 8)                { WAITV(0); }
        else                            { WAITV(12); }
        __builtin_amdgcn_s_barrier();
        __builtin_amdgcn_sched_barrier(0);

        // chunk-1 x prefetch at g=0 header (xq dead since prologue SETUP);
        // chunks 2,3 are prefetched inside the k4 loop right after their
        // predecessor's SETUP consumes xq (steps 8, 17).
        if (g == 0) LOAD_XQ(1);
        if (g < 7) STAGE(g + 2, (g + 2) % 3);

        const int bg = g % 3;
        short8 bfA[4], bfB[4];
        READ_BFR(bfA, bg, 0, 0);   // only exposed lgkm wait of the group

#pragma unroll
        for (int k4 = 0; k4 < 4; ++k4) {
            const int step = g * 4 + k4;
            const int kin = step % 9;

#pragma unroll
            for (int s = 0; s < 2; ++s) {
                // prefetch the NEXT half-step's fragments before this
                // half-step's MFMAs (covered by ~8 MFMAs of latency)
                if (s == 0) {
                    READ_BFR(bfB, bg, k4, 1);
                } else if (k4 < 3) {
                    READ_BFR(bfB, bg, k4 + 1, 0);
                }

#pragma unroll
                for (int m = 0; m < 2; ++m) {
                    union { ushort us[8]; short8 v; __hip_bfloat162 h2[4]; } pk;
#pragma unroll
                    for (int e = 0; e < 8; e += 2) {
                        pk.h2[e >> 1] = __float22bfloat162_rn(
                            make_float2(p[m][s][e], p[m][s][e + 1]));
                    }
#pragma unroll
                    for (int n = 0; n < 4; ++n)
                        acc[m][n] = __builtin_amdgcn_mfma_f32_16x16x32_bf16(
                            pk.v, bfA[n], acc[m][n], 0, 0, 0);
                    if (kin < NK - 1)
#pragma unroll
                        for (int e = 0; e < 8; ++e) p[m][s][e] *= r[m][s][e];
                }

                // rotate banks (static, SSA after full unroll)
                if (!(k4 == 3 && s == 1)) {
#pragma unroll
                    for (int n = 0; n < 4; ++n) bfA[n] = bfB[n];
                }
            }

            // chunk boundary (kin==8): old p,r dead; build next chunk's
            // basis from prefetched xq, THEN immediately re-arm xq with the
            // following chunk's x (R16-validated liveness).
            if (step == 8 || step == 17 || step == 26) {
                SETUP_FROM_XQ();
                if (step == 8)  LOAD_XQ(2);
                if (step == 17) LOAD_XQ(3);
            }
        }
    }

    // ---- epilogue: C/D layout col=lane&15, row=(lane>>4)*4+reg ----
#pragma unroll
    for (int m = 0; m < 2; ++m) {
#pragma unroll
        for (int n = 0; n < 4; ++n) {
            int col   = cg * 64 + n * 16 + (lane & 15);
            int rbase = rb + m * 16 + (lane >> 4) * 4;
#pragma unroll
            for (int reg = 0; reg < 4; ++reg) {
                out[(size_t)(rbase + reg) * ODIM + col] = acc[m][n][reg];
            }
        }
    }
#undef LOAD_XQ
#undef SETUP_FROM_XQ
#undef STAGE
#undef WAITV
#undef READ_BFR
}

extern "C" void kernel_launch(void* const* d_in, const int* in_sizes, int n_in,
                              void* d_out, int out_size, void* d_ws, size_t ws_size,
                              hipStream_t stream) {
    const float* x       = (const float*)d_in[0];   // [B, I]
    const float* weights = (const float*)d_in[1];   // [O, I]
    const float* coeffs  = (const float*)d_in[2];   // [O, I, 9]
    float* out = (float*)d_out;                     // [B, O]
    ushort* wc = (ushort*)d_ws;                     // 36 * 32 KB = 1.13 MB

    prep_wc3<<<256, 256, 0, stream>>>(weights, coeffs, wc);
    bern_gemm<<<256, 512, 0, stream>>>(x, wc, out);
}